// Round 14
// baseline (107.553 us; speedup 1.0000x reference)
//
#include <hip/hip_runtime.h>
#include <cstdint>
#include <cstddef>

typedef __attribute__((ext_vector_type(8))) _Float16 half8;
typedef __attribute__((ext_vector_type(4))) _Float16 half4;
typedef __attribute__((ext_vector_type(2))) __fp16 fp16x2;
typedef __attribute__((ext_vector_type(4))) float f32x4;

#define NB 2
#define NS 2048
#define ND 1024
#define NH 16
#define NHD 64
#define NM (NB * NS) /* 4096 */

// ---------------------------------------------------------------- prep (fused)
__device__ __forceinline__ void cvt8(const float* __restrict__ s,
                                     _Float16* __restrict__ d, int g) {
  const float4* s4 = (const float4*)s + (size_t)g * 2;
  float4 a = s4[0], b = s4[1];
  half8 h;
  h[0] = (_Float16)a.x; h[1] = (_Float16)a.y;
  h[2] = (_Float16)a.z; h[3] = (_Float16)a.w;
  h[4] = (_Float16)b.x; h[5] = (_Float16)b.y;
  h[6] = (_Float16)b.z; h[7] = (_Float16)b.w;
  *(half8*)(d + (size_t)g * 8) = h;
}

__global__ void prep(const float* __restrict__ x,
                     const float* __restrict__ wq, const float* __restrict__ wk,
                     const float* __restrict__ wv, const float* __restrict__ wo,
                     _Float16* __restrict__ xb,
                     _Float16* __restrict__ wqb, _Float16* __restrict__ wkb,
                     _Float16* __restrict__ wvb, _Float16* __restrict__ wob,
                     float* __restrict__ cosT, float* __restrict__ sinT) {
  int i = blockIdx.x * 256 + threadIdx.x;
  if (i < 524288) {
    cvt8(x, xb, i);
  } else if (i < 1048576) {
    int j = i - 524288;
    int k = j >> 17, g = j & 131071;
    const float* ws = (k == 0) ? wq : (k == 1) ? wk : (k == 2) ? wv : wo;
    _Float16* wd = (k == 0) ? wqb : (k == 1) ? wkb : (k == 2) ? wvb : wob;
    cvt8(ws, wd, g);
  } else if (i < 1056768) {
    int t0 = (i - 1048576) * 8;
#pragma unroll
    for (int e = 0; e < 8; ++e) {
      int t = t0 + e;
      int s = t >> 5, j = t & 31;
      float inv = expf(-(float)(2 * j) * (9.210340371976184f / 64.0f));
      float ang = (float)s * inv;
      cosT[t] = cosf(ang);
      sinT[t] = sinf(ang);
    }
  }
}

// ---------------------------------------------------------------- helpers
__device__ __forceinline__ void gload_lds16(const void* g, void* lds) {
  __builtin_amdgcn_global_load_lds(
      (const __attribute__((address_space(1))) unsigned int*)g,
      (__attribute__((address_space(3))) unsigned int*)lds, 16, 0, 0);
}

__device__ __forceinline__ float exp2_fast(float x) {
  float r;
  asm("v_exp_f32 %0, %1" : "=v"(r) : "v"(x));
  return r;
}

// ---------------------------------------------------------------- GEMM core
__device__ __forceinline__ void gemm_mainloop64(const _Float16* __restrict__ A,
                                                const _Float16* __restrict__ Bw,
                                                _Float16* As, _Float16* Bs,
                                                int brow, int bcol,
                                                int lane, int wid, int tid,
                                                f32x4 acc[4][4]) {
  const int l15 = lane & 15, l4 = lane >> 4;
  const int wr = wid >> 1, wc = wid & 1;
  const int rswz = (l15 & 7) << 4;
  const int srb = tid >> 3;
  const int scb = (tid & 7) * 16;

  for (int kt = 0; kt < ND / 64; ++kt) {
    const int k0 = kt * 64;
#pragma unroll
    for (int c = 0; c < 4; ++c) {
      const int r = c * 32 + srb;
      const int sb = scb ^ ((r & 7) << 4);
      gload_lds16((const char*)(A + (size_t)(brow + r) * ND + k0) + sb,
                  (char*)As + c * 4096 + tid * 16);
      gload_lds16((const char*)(Bw + (size_t)(bcol + r) * ND + k0) + sb,
                  (char*)Bs + c * 4096 + tid * 16);
    }
    __syncthreads();
#pragma unroll
    for (int kk = 0; kk < 2; ++kk) {
      half8 af[4], bf[4];
#pragma unroll
      for (int m = 0; m < 4; ++m) {
        const int row = wr * 64 + m * 16 + l15;
        af[m] = *(const half8*)((const char*)As +
                 ((row * 128 + kk * 64 + l4 * 16) ^ rswz));
      }
#pragma unroll
      for (int n = 0; n < 4; ++n) {
        const int row = wc * 64 + n * 16 + l15;
        bf[n] = *(const half8*)((const char*)Bs +
                 ((row * 128 + kk * 64 + l4 * 16) ^ rswz));
      }
#pragma unroll
      for (int m = 0; m < 4; ++m)
#pragma unroll
        for (int n = 0; n < 4; ++n)
          acc[m][n] = __builtin_amdgcn_mfma_f32_16x16x32_f16(af[m], bf[n],
                                                             acc[m][n], 0, 0, 0);
    }
    __syncthreads();
  }
}

// ---------------------------------------------------------------- QKV + RoPE
__launch_bounds__(256, 2)
__global__ void qkv_gemm(const _Float16* __restrict__ X,
                         const _Float16* __restrict__ Wq,
                         const _Float16* __restrict__ Wk,
                         const _Float16* __restrict__ Wv,
                         _Float16* __restrict__ Qb,
                         _Float16* __restrict__ Kb,
                         _Float16* __restrict__ Vt,
                         const float* __restrict__ cosT,
                         const float* __restrict__ sinT) {
  __shared__ __align__(16) _Float16 As[128 * 64];
  __shared__ __align__(16) _Float16 Bs[128 * 64];
  const int tid = threadIdx.x, lane = tid & 63, wid = tid >> 6;
  const int l15 = lane & 15, l4 = lane >> 4;
  const int wr = wid >> 1, wc = wid & 1;
  const int brow = blockIdx.y * 128, bcol = blockIdx.x * 128;
  const int mode = blockIdx.z;
  const _Float16* W = (mode == 0) ? Wq : (mode == 1 ? Wk : Wv);

  f32x4 acc[4][4] = {};
  gemm_mainloop64(X, W, As, Bs, brow, bcol, lane, wid, tid, acc);

  const int b = brow >> 11;
  const int sbase = (brow & (NS - 1)) + wr * 64;
  const int h = (bcol >> 6) + wc;

  if (mode < 2) {
    _Float16* oh = ((mode == 0) ? Qb : Kb) + (size_t)(b * NH + h) * NS * NHD;
#pragma unroll
    for (int m = 0; m < 4; ++m) {
#pragma unroll
      for (int r = 0; r < 4; ++r) {
        const int s = sbase + m * 16 + l4 * 4 + r;
#pragma unroll
        for (int n = 0; n < 2; ++n) {
          const int hd = n * 16 + l15;
          const float c = cosT[s * 32 + hd];
          const float sn = sinT[s * 32 + hd];
          const float lo = acc[m][n][r], hi = acc[m][n + 2][r];
          oh[(size_t)s * NHD + hd]      = (_Float16)(lo * c - hi * sn);
          oh[(size_t)s * NHD + hd + 32] = (_Float16)(hi * c + lo * sn);
        }
      }
    }
  } else {
    // V transposed + k-interleaved: newpos = (m>>1)*32 + l4*8 + (m&1)*4
#pragma unroll
    for (int m = 0; m < 4; ++m) {
      const int s0 = sbase + m * 16 + l4 * 4;
      const int npos = (s0 & ~63) + (m >> 1) * 32 + l4 * 8 + (m & 1) * 4;
#pragma unroll
      for (int n = 0; n < 4; ++n) {
        const int hd = n * 16 + l15;
        half4 pk;
        pk[0] = (_Float16)acc[m][n][0];
        pk[1] = (_Float16)acc[m][n][1];
        pk[2] = (_Float16)acc[m][n][2];
        pk[3] = (_Float16)acc[m][n][3];
        *(half4*)(Vt + ((size_t)(b * NH + h) * NHD + hd) * NS + npos) = pk;
      }
    }
  }
}

// ---------------------------------------------------------------- flash attn
// Split-K=2: block g=bid>>5, bh=bid&31; qt=31-(g>>1); s=1-(g&1).
// s=0 computes kt in [0,h), s=1 in [h,nkt), h=nkt/2. Grid 2048 -> CU queue
// stays full (sustained 4-5 blocks/CU). Per-iter body identical to R13.
// s=1 writes normalized O -> Ob; s=0 -> Op0 workspace; both write (m,l).
__launch_bounds__(256, 4)
__global__ void flash_attn(const _Float16* __restrict__ Qb,
                           const _Float16* __restrict__ Kb,
                           const _Float16* __restrict__ Vt,
                           _Float16* __restrict__ Ob,
                           _Float16* __restrict__ Op0,
                           float2* __restrict__ ml) {
  __shared__ __align__(16) _Float16 Ks[2][64 * 64];
  __shared__ __align__(16) _Float16 Vs[2][64 * 64];
  const int tid = threadIdx.x, lane = tid & 63, wid = tid >> 6;
  const int l15 = lane & 15, l4 = lane >> 4;
  const int bh = blockIdx.x & 31;
  const int g = blockIdx.x >> 5;
  const int qt = 31 - (g >> 1);
  const int sp = 1 - (g & 1);
  const int nkt = qt + 1;
  const int hsp = nkt >> 1;
  const int kt0 = sp ? hsp : 0;
  const int ktend = sp ? nkt : hsp;
  const _Float16* Qh = Qb + (size_t)bh * NS * NHD;
  const char* Kg = (const char*)(Kb + (size_t)bh * NS * NHD);
  const char* Vg = (const char*)(Vt + (size_t)bh * NHD * NS);

  const float K1 = 0.125f * 1.4426950408889634f;  // scale * log2(e)
  const int swz_lane = ((lane >> 3) & 7) << 4;
  const int qloc = wid * 16 + l15;
  const int rswz = (l15 & 7) << 4;
  const int b = bh >> 4, h = bh & 15;

  half8 qf[2];
#pragma unroll
  for (int kk = 0; kk < 2; ++kk)
    qf[kk] = *(const half8*)&Qh[(size_t)(qt * 64 + wid * 16 + l15) * NHD + kk * 32 + l4 * 8];

  f32x4 oacc[4] = {};
  float mrun = -3.0e38f, lrun = 0.f;

  if (kt0 < ktend) {
    // prologue: stage tile kt0 into buf 0
#pragma unroll
    for (int c = 0; c < 2; ++c) {
      const int chunk = wid * 2 + c;
      const int slot = chunk * 1024 + lane * 16;
      const int sw = slot ^ swz_lane;
      gload_lds16(Kg + (size_t)kt0 * 8192 + sw, (char*)&Ks[0][0] + slot);
      const int vrow = slot >> 7;
      gload_lds16(Vg + (size_t)vrow * (NS * 2) + kt0 * 128 + (sw & 127),
                  (char*)&Vs[0][0] + slot);
    }
    __syncthreads();

    int cur = 0;
    for (int kt = kt0; kt < ktend; ++kt) {
      if (kt + 1 < ktend) {  // prefetch next tile into cur^1
        const size_t knext = (size_t)(kt + 1);
#pragma unroll
        for (int c = 0; c < 2; ++c) {
          const int chunk = wid * 2 + c;
          const int slot = chunk * 1024 + lane * 16;
          const int sw = slot ^ swz_lane;
          gload_lds16(Kg + knext * 8192 + sw, (char*)&Ks[cur ^ 1][0] + slot);
          const int vrow = slot >> 7;
          gload_lds16(Vg + (size_t)vrow * (NS * 2) + knext * 128 + (sw & 127),
                      (char*)&Vs[cur ^ 1][0] + slot);
        }
      }

      const bool diag = (kt == qt);
      const char* Kbuf = (const char*)&Ks[cur][0];
      const char* Vbuf = (const char*)&Vs[cur][0];

      // ---- S^T = K Q^T
      f32x4 sacc[4] = {};
      __builtin_amdgcn_s_setprio(1);
#pragma unroll
      for (int kk = 0; kk < 2; ++kk) {
#pragma unroll
        for (int n = 0; n < 4; ++n) {
          if (diag && n > wid) continue;
          const int off = ((n * 16 + l15) * 128 + kk * 64 + l4 * 16) ^ rswz;
          half8 kf = *(const half8*)(Kbuf + off);
          sacc[n] = __builtin_amdgcn_mfma_f32_16x16x32_f16(kf, qf[kk], sacc[n], 0, 0, 0);
        }
      }
      __builtin_amdgcn_s_setprio(0);

      // ---- online softmax (reduced VALU)
      float traw[16];
#pragma unroll
      for (int n = 0; n < 4; ++n)
#pragma unroll
        for (int r = 0; r < 4; ++r) {
          float v = sacc[n][r];
          if (diag) {
            const int ki = n * 16 + l4 * 4 + r;
            v = (ki > qloc) ? -3.0e38f : v;
          }
          traw[n * 4 + r] = v;
        }
      float mx = traw[0];
#pragma unroll
      for (int j = 1; j < 16; ++j) mx = fmaxf(mx, traw[j]);
      mx = fmaxf(mx, __shfl_xor(mx, 16, 64));
      mx = fmaxf(mx, __shfl_xor(mx, 32, 64));
      mx *= K1;
      const float mnew = fmaxf(mrun, mx);
      const float alpha = exp2_fast(mrun - mnew);
      mrun = mnew;
      float ps[16], rs = 0.f;
#pragma unroll
      for (int j = 0; j < 16; ++j) {
        ps[j] = exp2_fast(__builtin_fmaf(traw[j], K1, -mnew));
        rs += ps[j];
      }
      rs += __shfl_xor(rs, 16, 64);
      rs += __shfl_xor(rs, 32, 64);
      lrun = lrun * alpha + rs;
#pragma unroll
      for (int n = 0; n < 4; ++n) oacc[n] *= alpha;

      // ---- PV (V k-interleaved: one b128 per (c,n))
      __builtin_amdgcn_s_setprio(1);
#pragma unroll
      for (int c = 0; c < 2; ++c) {
        if (diag && c == 1 && wid < 2) continue;
        half8 pb;
#pragma unroll
        for (int q2 = 0; q2 < 4; ++q2) {
          fp16x2 pp = __builtin_amdgcn_cvt_pkrtz(ps[8 * c + 2 * q2],
                                                 ps[8 * c + 2 * q2 + 1]);
          pb[2 * q2]     = (_Float16)pp[0];
          pb[2 * q2 + 1] = (_Float16)pp[1];
        }
#pragma unroll
        for (int n = 0; n < 4; ++n) {
          const int off = ((n * 16 + l15) * 128 + c * 64 + l4 * 16) ^ rswz;
          half8 va = *(const half8*)(Vbuf + off);
          oacc[n] = __builtin_amdgcn_mfma_f32_16x16x32_f16(va, pb, oacc[n], 0, 0, 0);
        }
      }
      __builtin_amdgcn_s_setprio(0);

      __syncthreads();
      cur ^= 1;
    }
  }

  // ---- epilogue: normalized partial + (m,l)
  const int q = qt * 64 + wid * 16 + l15;
  const float invl = (lrun > 0.f) ? 1.0f / lrun : 0.f;
  if (sp == 1) {
#pragma unroll
    for (int n = 0; n < 4; ++n) {
      f32x4 ov = oacc[n] * invl;
      half4 o;
      o[0] = (_Float16)ov[0];
      o[1] = (_Float16)ov[1];
      o[2] = (_Float16)ov[2];
      o[3] = (_Float16)ov[3];
      *(half4*)&Ob[((size_t)(b * NS + q)) * ND + h * NHD + n * 16 + l4 * 4] = o;
    }
  } else {
#pragma unroll
    for (int n = 0; n < 4; ++n) {
      f32x4 ov = oacc[n] * invl;
      half4 o;
      o[0] = (_Float16)ov[0];
      o[1] = (_Float16)ov[1];
      o[2] = (_Float16)ov[2];
      o[3] = (_Float16)ov[3];
      *(half4*)&Op0[((size_t)(bh * NS + q)) * NHD + n * 16 + l4 * 4] = o;
    }
  }
  if (l4 == 0) {
    float2 v;
    v.x = mrun;
    v.y = lrun;
    ml[(size_t)sp * (32 * NS) + bh * NS + q] = v;
  }
}

// ---------------------------------------------------------------- combine
// out = (O0*w0 + O1*w1), wi = 2^(mi-M)*li / sum. O1 partial lives in Ob.
__global__ void combine(const _Float16* __restrict__ Op0,
                        const float2* __restrict__ ml,
                        _Float16* __restrict__ Ob) {
  const int t = blockIdx.x * 256 + threadIdx.x;   // 0..524287
  const int r = t >> 3;                            // row 0..65535 = bh*2048+q
  const int c = (t & 7) * 8;
  const int bh = r >> 11, q = r & 2047;
  const float2 a = ml[r];
  const float2 bml = ml[32 * NS + r];
  const float M = fmaxf(a.x, bml.x);
  float w0 = exp2_fast(a.x - M) * a.y;
  float w1 = exp2_fast(bml.x - M) * bml.y;
  const float inv = 1.0f / (w0 + w1);
  w0 *= inv; w1 *= inv;
  const int b = bh >> 4, h = bh & 15;
  const size_t obi = ((size_t)(b * NS + q)) * ND + h * NHD + c;
  half8 o1 = *(const half8*)&Ob[obi];
  half8 o0 = *(const half8*)&Op0[(size_t)r * NHD + c];
  half8 o;
#pragma unroll
  for (int j = 0; j < 8; ++j)
    o[j] = (_Float16)((float)o0[j] * w0 + (float)o1[j] * w1);
  *(half8*)&Ob[obi] = o;
}

// ---------------------------------------------------------------- out proj
__launch_bounds__(256, 2)
__global__ void proj_gemm(const _Float16* __restrict__ A,
                          const _Float16* __restrict__ W,
                          float* __restrict__ out) {
  __shared__ __align__(16) _Float16 As[128 * 64];
  __shared__ __align__(16) _Float16 Bs[64 * 64];
  const int tid = threadIdx.x, lane = tid & 63, wid = tid >> 6;
  const int l15 = lane & 15, l4 = lane >> 4;
  const int wr = wid >> 1, wc = wid & 1;
  const int brow = blockIdx.y * 128, bcol = blockIdx.x * 64;
  const int rswz = (l15 & 7) << 4;
  const int srb = tid >> 3;
  const int scb = (tid & 7) * 16;

  f32x4 acc[4][2] = {};
  for (int kt = 0; kt < ND / 64; ++kt) {
    const int k0 = kt * 64;
#pragma unroll
    for (int c = 0; c < 4; ++c) {
      const int r = c * 32 + srb;
      const int sb = scb ^ ((r & 7) << 4);
      gload_lds16((const char*)(A + (size_t)(brow + r) * ND + k0) + sb,
                  (char*)As + c * 4096 + tid * 16);
    }
#pragma unroll
    for (int c = 0; c < 2; ++c) {
      const int r = c * 32 + srb;
      const int sb = scb ^ ((r & 7) << 4);
      gload_lds16((const char*)(W + (size_t)(bcol + r) * ND + k0) + sb,
                  (char*)Bs + c * 4096 + tid * 16);
    }
    __syncthreads();
#pragma unroll
    for (int kk = 0; kk < 2; ++kk) {
      half8 af[4], bf[2];
#pragma unroll
      for (int m = 0; m < 4; ++m) {
        const int row = wr * 64 + m * 16 + l15;
        af[m] = *(const half8*)((const char*)As +
                 ((row * 128 + kk * 64 + l4 * 16) ^ rswz));
      }
#pragma unroll
      for (int n = 0; n < 2; ++n) {
        const int row = wc * 32 + n * 16 + l15;
        bf[n] = *(const half8*)((const char*)Bs +
                 ((row * 128 + kk * 64 + l4 * 16) ^ rswz));
      }
#pragma unroll
      for (int m = 0; m < 4; ++m)
#pragma unroll
        for (int n = 0; n < 2; ++n)
          acc[m][n] = __builtin_amdgcn_mfma_f32_16x16x32_f16(af[m], bf[n],
                                                             acc[m][n], 0, 0, 0);
    }
    __syncthreads();
  }
#pragma unroll
  for (int m = 0; m < 4; ++m)
#pragma unroll
    for (int n = 0; n < 2; ++n)
#pragma unroll
      for (int r = 0; r < 4; ++r)
        out[(size_t)(brow + wr * 64 + m * 16 + l4 * 4 + r) * ND
            + bcol + wc * 32 + n * 16 + l15] = acc[m][n][r];
}

// ---------------------------------------------------------------- launch
extern "C" void kernel_launch(void* const* d_in, const int* in_sizes, int n_in,
                              void* d_out, int out_size, void* d_ws, size_t ws_size,
                              hipStream_t stream) {
  const float* x  = (const float*)d_in[0];
  const float* wq = (const float*)d_in[2];
  const float* wk = (const float*)d_in[3];
  const float* wv = (const float*)d_in[4];
  const float* wo = (const float*)d_in[5];
  float* out = (float*)d_out;

  char* w = (char*)d_ws;
  _Float16* xb   = (_Float16*)(w);                    // 8 MB  [4096][1024] (dead after qkv)
  _Float16* wqb  = (_Float16*)(w + (8ull  << 20));    // 2 MB (dead after qkv)
  _Float16* wkb  = (_Float16*)(w + (10ull << 20));    // 2 MB (dead after qkv)
  _Float16* wvb  = (_Float16*)(w + (12ull << 20));
  _Float16* wob  = (_Float16*)(w + (14ull << 20));
  _Float16* Qb   = (_Float16*)(w + (16ull << 20));    // 8 MB
  _Float16* Kb   = (_Float16*)(w + (24ull << 20));    // 8 MB
  _Float16* Vt   = (_Float16*)(w + (32ull << 20));    // 8 MB (k-interleaved)
  _Float16* Ob   = (_Float16*)(w + (40ull << 20));    // 8 MB
  float*    cosT = (float*)   (w + (48ull << 20));    // 256 KB
  float*    sinT = (float*)   (w + (48ull << 20) + (1ull << 18));
  // split-K reuse of dead regions:
  _Float16* Op0  = (_Float16*)(w);                    // 8 MB partial O (s=0), aliases xb
  float2*   ml   = (float2*)  (w + (10ull << 20));    // 1 MB (m,l) both splits, aliases wkb

  dim3 blk(256);
  prep<<<4128, blk, 0, stream>>>(x, wq, wk, wv, wo, xb, wqb, wkb, wvb, wob,
                                 cosT, sinT);
  qkv_gemm<<<dim3(8, 32, 3), blk, 0, stream>>>(xb, wqb, wkb, wvb, Qb, Kb, Vt,
                                               cosT, sinT);
  flash_attn<<<2048, blk, 0, stream>>>(Qb, Kb, Vt, Ob, Op0, ml);
  combine<<<2048, blk, 0, stream>>>(Op0, ml, Ob);
  proj_gemm<<<dim3(16, 32), blk, 0, stream>>>(Ob, wob, out);
}

// Round 15
// 99.616 us; speedup vs baseline: 1.0797x; 1.0797x over previous
//
#include <hip/hip_runtime.h>
#include <cstdint>
#include <cstddef>

typedef __attribute__((ext_vector_type(8))) _Float16 half8;
typedef __attribute__((ext_vector_type(4))) _Float16 half4;
typedef __attribute__((ext_vector_type(2))) __fp16 fp16x2;
typedef __attribute__((ext_vector_type(4))) float f32x4;

#define NB 2
#define NS 2048
#define ND 1024
#define NH 16
#define NHD 64
#define NM (NB * NS) /* 4096 */

// ---------------------------------------------------------------- prep (fused)
__device__ __forceinline__ void cvt8(const float* __restrict__ s,
                                     _Float16* __restrict__ d, int g) {
  const float4* s4 = (const float4*)s + (size_t)g * 2;
  float4 a = s4[0], b = s4[1];
  half8 h;
  h[0] = (_Float16)a.x; h[1] = (_Float16)a.y;
  h[2] = (_Float16)a.z; h[3] = (_Float16)a.w;
  h[4] = (_Float16)b.x; h[5] = (_Float16)b.y;
  h[6] = (_Float16)b.z; h[7] = (_Float16)b.w;
  *(half8*)(d + (size_t)g * 8) = h;
}

__global__ void prep(const float* __restrict__ x,
                     const float* __restrict__ wq, const float* __restrict__ wk,
                     const float* __restrict__ wv, const float* __restrict__ wo,
                     _Float16* __restrict__ xb,
                     _Float16* __restrict__ wqb, _Float16* __restrict__ wkb,
                     _Float16* __restrict__ wvb, _Float16* __restrict__ wob,
                     float* __restrict__ cosT, float* __restrict__ sinT) {
  int i = blockIdx.x * 256 + threadIdx.x;
  if (i < 524288) {
    cvt8(x, xb, i);
  } else if (i < 1048576) {
    int j = i - 524288;
    int k = j >> 17, g = j & 131071;
    const float* ws = (k == 0) ? wq : (k == 1) ? wk : (k == 2) ? wv : wo;
    _Float16* wd = (k == 0) ? wqb : (k == 1) ? wkb : (k == 2) ? wvb : wob;
    cvt8(ws, wd, g);
  } else if (i < 1056768) {
    int t0 = (i - 1048576) * 8;
#pragma unroll
    for (int e = 0; e < 8; ++e) {
      int t = t0 + e;
      int s = t >> 5, j = t & 31;
      float inv = expf(-(float)(2 * j) * (9.210340371976184f / 64.0f));
      float ang = (float)s * inv;
      cosT[t] = cosf(ang);
      sinT[t] = sinf(ang);
    }
  }
}

// ---------------------------------------------------------------- helpers
__device__ __forceinline__ void gload_lds16(const void* g, void* lds) {
  __builtin_amdgcn_global_load_lds(
      (const __attribute__((address_space(1))) unsigned int*)g,
      (__attribute__((address_space(3))) unsigned int*)lds, 16, 0, 0);
}

__device__ __forceinline__ float exp2_fast(float x) {
  float r;
  asm("v_exp_f32 %0, %1" : "=v"(r) : "v"(x));
  return r;
}

// ---------------------------------------------------------------- GEMM core
// BK=64 mainloop: tiles [rows][64] f16, row stride 128B, XOR-swizzled
// (byte ^ (row&7)<<4) with pre-swizzled global source. 16 K-iters, 2 kk each.
__device__ __forceinline__ void gemm_mainloop64(const _Float16* __restrict__ A,
                                                const _Float16* __restrict__ Bw,
                                                _Float16* As, _Float16* Bs,
                                                int brow, int bcol,
                                                int lane, int wid, int tid,
                                                f32x4 acc[4][4]) {
  const int l15 = lane & 15, l4 = lane >> 4;
  const int wr = wid >> 1, wc = wid & 1;
  const int rswz = (l15 & 7) << 4;
  const int srb = tid >> 3;
  const int scb = (tid & 7) * 16;

  for (int kt = 0; kt < ND / 64; ++kt) {
    const int k0 = kt * 64;
#pragma unroll
    for (int c = 0; c < 4; ++c) {
      const int r = c * 32 + srb;
      const int sb = scb ^ ((r & 7) << 4);
      gload_lds16((const char*)(A + (size_t)(brow + r) * ND + k0) + sb,
                  (char*)As + c * 4096 + tid * 16);
      gload_lds16((const char*)(Bw + (size_t)(bcol + r) * ND + k0) + sb,
                  (char*)Bs + c * 4096 + tid * 16);
    }
    __syncthreads();
#pragma unroll
    for (int kk = 0; kk < 2; ++kk) {
      half8 af[4], bf[4];
#pragma unroll
      for (int m = 0; m < 4; ++m) {
        const int row = wr * 64 + m * 16 + l15;
        af[m] = *(const half8*)((const char*)As +
                 ((row * 128 + kk * 64 + l4 * 16) ^ rswz));
      }
#pragma unroll
      for (int n = 0; n < 4; ++n) {
        const int row = wc * 64 + n * 16 + l15;
        bf[n] = *(const half8*)((const char*)Bs +
                 ((row * 128 + kk * 64 + l4 * 16) ^ rswz));
      }
#pragma unroll
      for (int m = 0; m < 4; ++m)
#pragma unroll
        for (int n = 0; n < 4; ++n)
          acc[m][n] = __builtin_amdgcn_mfma_f32_16x16x32_f16(af[m], bf[n],
                                                             acc[m][n], 0, 0, 0);
    }
    __syncthreads();
  }
}

// ---------------------------------------------------------------- QKV + RoPE
// grid 768 = exactly 3 blocks/CU; min-waves 3 makes the whole launch
// co-resident (m114 overlap mechanism; was capped at 2/CU before).
__launch_bounds__(256, 3)
__global__ void qkv_gemm(const _Float16* __restrict__ X,
                         const _Float16* __restrict__ Wq,
                         const _Float16* __restrict__ Wk,
                         const _Float16* __restrict__ Wv,
                         _Float16* __restrict__ Qb,
                         _Float16* __restrict__ Kb,
                         _Float16* __restrict__ Vt,
                         const float* __restrict__ cosT,
                         const float* __restrict__ sinT) {
  __shared__ __align__(16) _Float16 As[128 * 64];
  __shared__ __align__(16) _Float16 Bs[128 * 64];
  const int tid = threadIdx.x, lane = tid & 63, wid = tid >> 6;
  const int l15 = lane & 15, l4 = lane >> 4;
  const int wr = wid >> 1, wc = wid & 1;
  const int brow = blockIdx.y * 128, bcol = blockIdx.x * 128;
  const int mode = blockIdx.z;
  const _Float16* W = (mode == 0) ? Wq : (mode == 1 ? Wk : Wv);

  f32x4 acc[4][4] = {};
  gemm_mainloop64(X, W, As, Bs, brow, bcol, lane, wid, tid, acc);

  const int b = brow >> 11;
  const int sbase = (brow & (NS - 1)) + wr * 64;
  const int h = (bcol >> 6) + wc;

  if (mode < 2) {
    _Float16* oh = ((mode == 0) ? Qb : Kb) + (size_t)(b * NH + h) * NS * NHD;
#pragma unroll
    for (int m = 0; m < 4; ++m) {
#pragma unroll
      for (int r = 0; r < 4; ++r) {
        const int s = sbase + m * 16 + l4 * 4 + r;
#pragma unroll
        for (int n = 0; n < 2; ++n) {
          const int hd = n * 16 + l15;
          const float c = cosT[s * 32 + hd];
          const float sn = sinT[s * 32 + hd];
          const float lo = acc[m][n][r], hi = acc[m][n + 2][r];
          oh[(size_t)s * NHD + hd]      = (_Float16)(lo * c - hi * sn);
          oh[(size_t)s * NHD + hd + 32] = (_Float16)(hi * c + lo * sn);
        }
      }
    }
  } else {
    // V transposed + k-interleaved: newpos = (m>>1)*32 + l4*8 + (m&1)*4
#pragma unroll
    for (int m = 0; m < 4; ++m) {
      const int s0 = sbase + m * 16 + l4 * 4;
      const int npos = (s0 & ~63) + (m >> 1) * 32 + l4 * 8 + (m & 1) * 4;
#pragma unroll
      for (int n = 0; n < 4; ++n) {
        const int hd = n * 16 + l15;
        half4 pk;
        pk[0] = (_Float16)acc[m][n][0];
        pk[1] = (_Float16)acc[m][n][1];
        pk[2] = (_Float16)acc[m][n][2];
        pk[3] = (_Float16)acc[m][n][3];
        *(half4*)(Vt + ((size_t)(b * NH + h) * NHD + hd) * NS + npos) = pk;
      }
    }
  }
}

// ---------------------------------------------------------------- flash attn
// One q-tile per block, grid 1024, LONGEST-FIRST dispatch (qt = 31 - bid>>5).
// min-waves 5 opens a 5th block slot per CU (32KB LDS x5 = 160KB) so
// finishing blocks' slots refill promptly. Body identical to R13.
__launch_bounds__(256, 5)
__global__ void flash_attn(const _Float16* __restrict__ Qb,
                           const _Float16* __restrict__ Kb,
                           const _Float16* __restrict__ Vt,
                           _Float16* __restrict__ Ob) {
  __shared__ __align__(16) _Float16 Ks[2][64 * 64];
  __shared__ __align__(16) _Float16 Vs[2][64 * 64];
  const int tid = threadIdx.x, lane = tid & 63, wid = tid >> 6;
  const int l15 = lane & 15, l4 = lane >> 4;
  const int bh = blockIdx.x & 31;
  const int qt = 31 - (blockIdx.x >> 5);
  const _Float16* Qh = Qb + (size_t)bh * NS * NHD;
  const char* Kg = (const char*)(Kb + (size_t)bh * NS * NHD);
  const char* Vg = (const char*)(Vt + (size_t)bh * NHD * NS);

  const float K1 = 0.125f * 1.4426950408889634f;  // scale * log2(e)
  const int swz_lane = ((lane >> 3) & 7) << 4;
  const int qloc = wid * 16 + l15;
  const int rswz = (l15 & 7) << 4;
  const int b = bh >> 4, h = bh & 15;
  const int nkt = qt + 1;

  half8 qf[2];
#pragma unroll
  for (int kk = 0; kk < 2; ++kk)
    qf[kk] = *(const half8*)&Qh[(size_t)(qt * 64 + wid * 16 + l15) * NHD + kk * 32 + l4 * 8];

  f32x4 oacc[4] = {};
  float mrun = -3.0e38f, lrun = 0.f;

  // prologue: stage tile 0 into buf 0
#pragma unroll
  for (int c = 0; c < 2; ++c) {
    const int chunk = wid * 2 + c;
    const int slot = chunk * 1024 + lane * 16;
    const int sw = slot ^ swz_lane;
    gload_lds16(Kg + sw, (char*)&Ks[0][0] + slot);
    const int vrow = slot >> 7;
    gload_lds16(Vg + (size_t)vrow * (NS * 2) + (sw & 127), (char*)&Vs[0][0] + slot);
  }
  __syncthreads();

  int cur = 0;
  for (int kt = 0; kt < nkt; ++kt) {
    if (kt + 1 < nkt) {  // prefetch next tile into cur^1
      const size_t knext = (size_t)(kt + 1);
#pragma unroll
      for (int c = 0; c < 2; ++c) {
        const int chunk = wid * 2 + c;
        const int slot = chunk * 1024 + lane * 16;
        const int sw = slot ^ swz_lane;
        gload_lds16(Kg + knext * 8192 + sw, (char*)&Ks[cur ^ 1][0] + slot);
        const int vrow = slot >> 7;
        gload_lds16(Vg + (size_t)vrow * (NS * 2) + knext * 128 + (sw & 127),
                    (char*)&Vs[cur ^ 1][0] + slot);
      }
    }

    const bool diag = (kt == qt);
    const char* Kbuf = (const char*)&Ks[cur][0];
    const char* Vbuf = (const char*)&Vs[cur][0];

    // ---- S^T = K Q^T
    f32x4 sacc[4] = {};
    __builtin_amdgcn_s_setprio(1);
#pragma unroll
    for (int kk = 0; kk < 2; ++kk) {
#pragma unroll
      for (int n = 0; n < 4; ++n) {
        if (diag && n > wid) continue;
        const int off = ((n * 16 + l15) * 128 + kk * 64 + l4 * 16) ^ rswz;
        half8 kf = *(const half8*)(Kbuf + off);
        sacc[n] = __builtin_amdgcn_mfma_f32_16x16x32_f16(kf, qf[kk], sacc[n], 0, 0, 0);
      }
    }
    __builtin_amdgcn_s_setprio(0);

    // ---- online softmax (reduced VALU)
    float traw[16];
#pragma unroll
    for (int n = 0; n < 4; ++n)
#pragma unroll
      for (int r = 0; r < 4; ++r) {
        float v = sacc[n][r];
        if (diag) {
          const int ki = n * 16 + l4 * 4 + r;
          v = (ki > qloc) ? -3.0e38f : v;
        }
        traw[n * 4 + r] = v;
      }
    float mx = traw[0];
#pragma unroll
    for (int j = 1; j < 16; ++j) mx = fmaxf(mx, traw[j]);
    mx = fmaxf(mx, __shfl_xor(mx, 16, 64));
    mx = fmaxf(mx, __shfl_xor(mx, 32, 64));
    mx *= K1;
    const float mnew = fmaxf(mrun, mx);
    const float alpha = exp2_fast(mrun - mnew);
    mrun = mnew;
    float ps[16], rs = 0.f;
#pragma unroll
    for (int j = 0; j < 16; ++j) {
      ps[j] = exp2_fast(__builtin_fmaf(traw[j], K1, -mnew));
      rs += ps[j];
    }
    rs += __shfl_xor(rs, 16, 64);
    rs += __shfl_xor(rs, 32, 64);
    lrun = lrun * alpha + rs;
#pragma unroll
    for (int n = 0; n < 4; ++n) oacc[n] *= alpha;

    // ---- PV (V k-interleaved: one b128 per (c,n))
    __builtin_amdgcn_s_setprio(1);
#pragma unroll
    for (int c = 0; c < 2; ++c) {
      if (diag && c == 1 && wid < 2) continue;
      half8 pb;
#pragma unroll
      for (int q2 = 0; q2 < 4; ++q2) {
        fp16x2 pp = __builtin_amdgcn_cvt_pkrtz(ps[8 * c + 2 * q2],
                                               ps[8 * c + 2 * q2 + 1]);
        pb[2 * q2]     = (_Float16)pp[0];
        pb[2 * q2 + 1] = (_Float16)pp[1];
      }
#pragma unroll
      for (int n = 0; n < 4; ++n) {
        const int off = ((n * 16 + l15) * 128 + c * 64 + l4 * 16) ^ rswz;
        half8 va = *(const half8*)(Vbuf + off);
        oacc[n] = __builtin_amdgcn_mfma_f32_16x16x32_f16(va, pb, oacc[n], 0, 0, 0);
      }
    }
    __builtin_amdgcn_s_setprio(0);

    __syncthreads();
    cur ^= 1;
  }

  // ---- epilogue (registers + global only; no LDS)
  const int s = qt * 64 + wid * 16 + l15;
  const float invl = 1.0f / lrun;
#pragma unroll
  for (int n = 0; n < 4; ++n) {
    f32x4 ov = oacc[n] * invl;
    half4 o;
    o[0] = (_Float16)ov[0];
    o[1] = (_Float16)ov[1];
    o[2] = (_Float16)ov[2];
    o[3] = (_Float16)ov[3];
    *(half4*)&Ob[((size_t)(b * NS + s)) * ND + h * NHD + n * 16 + l4 * 4] = o;
  }
}

// ---------------------------------------------------------------- out proj
// BM=128, BN=64, BK=64 (swizzled). Grid (16,32) = 512 blocks = 2/CU resident.
__launch_bounds__(256, 2)
__global__ void proj_gemm(const _Float16* __restrict__ A,
                          const _Float16* __restrict__ W,
                          float* __restrict__ out) {
  __shared__ __align__(16) _Float16 As[128 * 64];
  __shared__ __align__(16) _Float16 Bs[64 * 64];
  const int tid = threadIdx.x, lane = tid & 63, wid = tid >> 6;
  const int l15 = lane & 15, l4 = lane >> 4;
  const int wr = wid >> 1, wc = wid & 1;
  const int brow = blockIdx.y * 128, bcol = blockIdx.x * 64;
  const int rswz = (l15 & 7) << 4;
  const int srb = tid >> 3;
  const int scb = (tid & 7) * 16;

  f32x4 acc[4][2] = {};
  for (int kt = 0; kt < ND / 64; ++kt) {
    const int k0 = kt * 64;
#pragma unroll
    for (int c = 0; c < 4; ++c) {
      const int r = c * 32 + srb;
      const int sb = scb ^ ((r & 7) << 4);
      gload_lds16((const char*)(A + (size_t)(brow + r) * ND + k0) + sb,
                  (char*)As + c * 4096 + tid * 16);
    }
#pragma unroll
    for (int c = 0; c < 2; ++c) {
      const int r = c * 32 + srb;
      const int sb = scb ^ ((r & 7) << 4);
      gload_lds16((const char*)(W + (size_t)(bcol + r) * ND + k0) + sb,
                  (char*)Bs + c * 4096 + tid * 16);
    }
    __syncthreads();
#pragma unroll
    for (int kk = 0; kk < 2; ++kk) {
      half8 af[4], bf[2];
#pragma unroll
      for (int m = 0; m < 4; ++m) {
        const int row = wr * 64 + m * 16 + l15;
        af[m] = *(const half8*)((const char*)As +
                 ((row * 128 + kk * 64 + l4 * 16) ^ rswz));
      }
#pragma unroll
      for (int n = 0; n < 2; ++n) {
        const int row = wc * 32 + n * 16 + l15;
        bf[n] = *(const half8*)((const char*)Bs +
                 ((row * 128 + kk * 64 + l4 * 16) ^ rswz));
      }
#pragma unroll
      for (int m = 0; m < 4; ++m)
#pragma unroll
        for (int n = 0; n < 2; ++n)
          acc[m][n] = __builtin_amdgcn_mfma_f32_16x16x32_f16(af[m], bf[n],
                                                             acc[m][n], 0, 0, 0);
    }
    __syncthreads();
  }
#pragma unroll
  for (int m = 0; m < 4; ++m)
#pragma unroll
    for (int n = 0; n < 2; ++n)
#pragma unroll
      for (int r = 0; r < 4; ++r)
        out[(size_t)(brow + wr * 64 + m * 16 + l4 * 4 + r) * ND
            + bcol + wc * 32 + n * 16 + l15] = acc[m][n][r];
}

// ---------------------------------------------------------------- launch
extern "C" void kernel_launch(void* const* d_in, const int* in_sizes, int n_in,
                              void* d_out, int out_size, void* d_ws, size_t ws_size,
                              hipStream_t stream) {
  const float* x  = (const float*)d_in[0];
  const float* wq = (const float*)d_in[2];
  const float* wk = (const float*)d_in[3];
  const float* wv = (const float*)d_in[4];
  const float* wo = (const float*)d_in[5];
  float* out = (float*)d_out;

  char* w = (char*)d_ws;
  _Float16* xb   = (_Float16*)(w);                    // 8 MB  [4096][1024]
  _Float16* wqb  = (_Float16*)(w + (8ull  << 20));    // 2 MB
  _Float16* wkb  = (_Float16*)(w + (10ull << 20));
  _Float16* wvb  = (_Float16*)(w + (12ull << 20));
  _Float16* wob  = (_Float16*)(w + (14ull << 20));
  _Float16* Qb   = (_Float16*)(w + (16ull << 20));    // 8 MB  [32][2048][64]
  _Float16* Kb   = (_Float16*)(w + (24ull << 20));    // 8 MB
  _Float16* Vt   = (_Float16*)(w + (32ull << 20));    // 8 MB  [32][64][2048] (k-interleaved)
  _Float16* Ob   = (_Float16*)(w + (40ull << 20));    // 8 MB  [4096][1024]
  float*    cosT = (float*)   (w + (48ull << 20));    // 256 KB [2048][32]
  float*    sinT = (float*)   (w + (48ull << 20) + (1ull << 18));

  dim3 blk(256);
  prep<<<4128, blk, 0, stream>>>(x, wq, wk, wv, wo, xb, wqb, wkb, wvb, wob,
                                 cosT, sinT);
  qkv_gemm<<<dim3(8, 32, 3), blk, 0, stream>>>(xb, wqb, wkb, wvb, Qb, Kb, Vt,
                                               cosT, sinT);
  flash_attn<<<1024, blk, 0, stream>>>(Qb, Kb, Vt, Ob);
  proj_gemm<<<dim3(16, 32), blk, 0, stream>>>(Ob, wob, out);
}